// Round 9
// baseline (290.063 us; speedup 1.0000x reference)
//
#include <hip/hip_runtime.h>
#include <hip/hip_bf16.h>

#define NE 8
#define HD 1024
#define ID 2816
#define TT 4096
#define BM 128
#define BK 32
#define BN1 64
#define BN2 64
#define MAXMT (TT / BM + NE) /* 40 worst-case M-tiles */
#define NKS1 (HD / BK)  /* 32 */
#define NKS2 (ID / BK)  /* 88 */

typedef __attribute__((ext_vector_type(4))) float f32x4;
typedef __attribute__((ext_vector_type(8))) short s16x8;
typedef __attribute__((ext_vector_type(4))) int i32x4;

// fp32x2 -> packed bf16x2 (RNE, v_cvt_pk_bf16_f32)
__device__ __forceinline__ unsigned int f2bfpk(float lo, float hi) {
  float2 t; t.x = lo; t.y = hi;
  union { __hip_bfloat162 h2; unsigned int u; } cv;
  cv.h2 = __float22bfloat162_rn(t);
  return cv.u;
}

// barrier that does NOT drain vmcnt: prefetch loads stay in flight
__device__ __forceinline__ void lds_barrier() {
  asm volatile("s_waitcnt lgkmcnt(0)" ::: "memory");
  __builtin_amdgcn_s_barrier();
}

__device__ __forceinline__ bool map_tile(const void* bsp, int mt, int& e,
                                         int& mstart, int& rowend) {
  const int* w = (const int*)bsp;
  bool is64 = (w[1] == 0) && (w[3] == 0) && (w[5] == 0) && (w[7] == 0) &&
              ((w[0] | w[2] | w[4] | w[6]) != 0);
  long long start = 0;
  int rem = mt;
  for (int i = 0; i < NE; ++i) {
    long long b = is64 ? ((const long long*)bsp)[i] : (long long)w[i];
    if (b < 0) b = 0;
    int tiles = (int)((b + BM - 1) / BM);
    if (rem < tiles) {
      long long m0 = start + (long long)rem * BM;
      long long me = start + b;
      if (m0 >= TT) return false;
      if (me > TT) me = TT;
      e = i; mstart = (int)m0; rowend = (int)me;
      return true;
    }
    rem -= tiles;
    start += b;
  }
  return false;
}

// ---------------- Kernel 0: x (fp32) -> xbf (bf16, row-major) ----------------
__global__ __launch_bounds__(256) void cvt_x(const float* __restrict__ x,
                                             __hip_bfloat16* __restrict__ xb) {
  size_t i = ((size_t)blockIdx.x * 256 + threadIdx.x) * 8;
  f32x4 v0 = *(const f32x4*)(x + i);
  f32x4 v1 = *(const f32x4*)(x + i + 4);
  s16x8 o;
  unsigned int p0 = f2bfpk(v0[0], v0[1]), p1 = f2bfpk(v0[2], v0[3]);
  unsigned int p2 = f2bfpk(v1[0], v1[1]), p3 = f2bfpk(v1[2], v1[3]);
  o[0] = (short)(p0 & 0xffff); o[1] = (short)(p0 >> 16);
  o[2] = (short)(p1 & 0xffff); o[3] = (short)(p1 >> 16);
  o[4] = (short)(p2 & 0xffff); o[5] = (short)(p2 >> 16);
  o[6] = (short)(p3 & 0xffff); o[7] = (short)(p3 >> 16);
  *(s16x8*)((unsigned short*)xb + i) = o;
}

// ---------------- Kernel 1: up = silu(x@w1[e]) * (x@w3[e]) ----------------
// 256 thr, 4 waves (2m x 2n, 64x32/wave), BM=128 BN=64 BK=32, dual acc.
// A: DIRECT global b128 fragment loads from row-major xbf (16B contiguous
//    per lane; L2/L3-hot, shared by 22 n-blocks), 2-slot register prefetch.
//    NO A LDS, no glds. B: frag-order LDS (1 b128 write, 2 b128 reads per
//    matrix per wave), double-buffered. 6 LDS ops/wave/k-step (was 12).
__global__ __launch_bounds__(256, 3) void moe_gemm1(
    const __hip_bfloat16* __restrict__ xbf, const float* __restrict__ w1,
    const float* __restrict__ w3, const void* __restrict__ bsp,
    __hip_bfloat16* __restrict__ up) {
  __shared__ __align__(16) char B1s[2][4096];  // 8192
  __shared__ __align__(16) char B3s[2][4096];  // 8192 -> 16KB total

  const int NWG = (ID / BN1) * MAXMT;  // 44*40 = 1760, %8==0
  int bid = blockIdx.x;
  int logical = (bid & 7) * (NWG >> 3) + (bid >> 3);
  int mt = logical % MAXMT;
  int nt = logical / MAXMT;
  int e, mstart, rowend;
  if (!map_tile(bsp, mt, e, mstart, rowend)) return;
  const int n0 = nt * BN1;
  const int tid = threadIdx.x;
  const int lane = tid & 63;
  const int wv = tid >> 6;
  const int wr = wv >> 1, wc = wv & 1;
  const int q = lane >> 4, r16 = lane & 15;

  // B staging: thread (b_n, b_kq) owns col n0+b_n, k = 8*b_kq .. +7
  const int b_n = tid & 63, b_kq = tid >> 6;
  const int boff = (b_n >> 4) * 1024 + b_kq * 256 + (b_n & 15) * 16;
  const float* w1c = w1 + (size_t)e * HD * ID + (size_t)(8 * b_kq) * ID + n0 + b_n;
  const float* w3c = w3 + (size_t)e * HD * ID + (size_t)(8 * b_kq) * ID + n0 + b_n;

  // A fragment base pointers (row-major xbf), row clamped to TT-1 (no OOB;
  // rows >= rowend compute garbage that the guarded epilogue discards)
  const unsigned short* pA0;
  const unsigned short* pA1;
  const unsigned short* pA2;
  const unsigned short* pA3;
  {
    const unsigned short* xb = (const unsigned short*)xbf;
    int r0 = mstart + wr * 64 + r16;
    int rowA[4];
#pragma unroll
    for (int i = 0; i < 4; ++i) {
      int r = r0 + i * 16;
      rowA[i] = r < TT ? r : TT - 1;
    }
    pA0 = xb + (size_t)rowA[0] * HD + q * 8;
    pA1 = xb + (size_t)rowA[1] * HD + q * 8;
    pA2 = xb + (size_t)rowA[2] * HD + q * 8;
    pA3 = xb + (size_t)rowA[3] * HD + q * 8;
  }

  f32x4 acc1[4][2], acc3[4][2];
#pragma unroll
  for (int i = 0; i < 4; ++i)
#pragma unroll
    for (int j = 0; j < 2; ++j) { acc1[i][j] = (f32x4)0.f; acc3[i][j] = (f32x4)0.f; }

  s16x8 Aa[4], Ab[4];
  float Wa1[8], Wa3[8], Wb1[8], Wb3[8];

  auto loadA = [&](s16x8* A, int k) {
    A[0] = *(const s16x8*)(pA0 + k * BK);
    A[1] = *(const s16x8*)(pA1 + k * BK);
    A[2] = *(const s16x8*)(pA2 + k * BK);
    A[3] = *(const s16x8*)(pA3 + k * BK);
  };
  auto loadB = [&](float* W1_, float* W3_) {
#pragma unroll
    for (int i = 0; i < 8; ++i) {
      W1_[i] = w1c[(size_t)i * ID];
      W3_[i] = w3c[(size_t)i * ID];
    }
    w1c += (size_t)BK * ID; w3c += (size_t)BK * ID;
  };
  auto storeB = [&](int buf, const float* W1_, const float* W3_) {
    i32x4 p1, p3;
    p1[0] = (int)f2bfpk(W1_[0], W1_[1]); p1[1] = (int)f2bfpk(W1_[2], W1_[3]);
    p1[2] = (int)f2bfpk(W1_[4], W1_[5]); p1[3] = (int)f2bfpk(W1_[6], W1_[7]);
    *(i32x4*)(B1s[buf] + boff) = p1;
    p3[0] = (int)f2bfpk(W3_[0], W3_[1]); p3[1] = (int)f2bfpk(W3_[2], W3_[3]);
    p3[2] = (int)f2bfpk(W3_[4], W3_[5]); p3[3] = (int)f2bfpk(W3_[6], W3_[7]);
    *(i32x4*)(B3s[buf] + boff) = p3;
  };
  auto compute = [&](const s16x8* A, int bb) {
    s16x8 b1[2], b3[2];
#pragma unroll
    for (int j = 0; j < 2; ++j) {
      b1[j] = *(const s16x8*)(B1s[bb] + (wc * 2 + j) * 1024 + lane * 16);
      b3[j] = *(const s16x8*)(B3s[bb] + (wc * 2 + j) * 1024 + lane * 16);
    }
#pragma unroll
    for (int i = 0; i < 4; ++i)
#pragma unroll
      for (int j = 0; j < 2; ++j) {
        acc1[i][j] = __builtin_amdgcn_mfma_f32_16x16x32_bf16(A[i], b1[j], acc1[i][j], 0, 0, 0);
        acc3[i][j] = __builtin_amdgcn_mfma_f32_16x16x32_bf16(A[i], b3[j], acc3[i][j], 0, 0, 0);
      }
  };

  // prologue
  loadA(Aa, 0); loadA(Ab, 1);
  loadB(Wa1, Wa3);   // B(0)
  loadB(Wb1, Wb3);   // B(1)
  storeB(0, Wa1, Wa3);
  lds_barrier();
  for (int kt = 0; kt < NKS1; kt += 2) {
    // phase A: tile kt (A regs Aa, B lds0)
    if (kt + 2 < NKS1) loadB(Wa1, Wa3);          // B(kt+2) -> Wa
    compute(Aa, 0);
    if (kt + 2 < NKS1) loadA(Aa, kt + 2);        // A(kt+2)
    if (kt + 1 < NKS1) { storeB(1, Wb1, Wb3); lds_barrier(); }
    // phase B: tile kt+1 (A regs Ab, B lds1)
    if (kt + 3 < NKS1) loadB(Wb1, Wb3);          // B(kt+3) -> Wb
    compute(Ab, 1);
    if (kt + 3 < NKS1) loadA(Ab, kt + 3);
    if (kt + 2 < NKS1) { storeB(0, Wa1, Wa3); lds_barrier(); }
  }

  // epilogue: silu(acc1)*acc3 -> bf16
#pragma unroll
  for (int i = 0; i < 4; ++i)
#pragma unroll
    for (int r = 0; r < 4; ++r) {
      int gm = mstart + wr * 64 + i * 16 + q * 4 + r;
      if (gm < rowend) {
#pragma unroll
        for (int j = 0; j < 2; ++j) {
          float v1 = acc1[i][j][r], v3 = acc3[i][j][r];
          float s = v1 / (1.f + __expf(-v1));
          up[(size_t)gm * ID + n0 + wc * 32 + j * 16 + r16] = __float2bfloat16(s * v3);
        }
      }
    }
}

// ---------------- Kernel 2: out = up @ w2[e] ----------------
// 256 thr, 128x64, 4 waves. A direct global b128 frags from row-major up
// (L2-hot, shared by 16 n-blocks). B frag-order LDS. 3 LDS ops/wave/k-step.
__global__ __launch_bounds__(256, 4) void moe_gemm2(
    const __hip_bfloat16* __restrict__ up, const float* __restrict__ w2,
    const void* __restrict__ bsp, float* __restrict__ out) {
  __shared__ __align__(16) char Bs[2][4096];  // 8192

  const int NWG = (HD / BN2) * MAXMT;  // 640, %8==0
  int bid = blockIdx.x;
  int logical = (bid & 7) * (NWG >> 3) + (bid >> 3);
  int mt = logical % MAXMT;
  int nt = logical / MAXMT;
  int e, mstart, rowend;
  if (!map_tile(bsp, mt, e, mstart, rowend)) return;
  const int n0 = nt * BN2;
  const int tid = threadIdx.x;
  const int lane = tid & 63;
  const int wv = tid >> 6;
  const int wr = wv >> 1, wc = wv & 1;
  const int q = lane >> 4, r16 = lane & 15;

  const int b_n = tid & 63, b_kq = tid >> 6;
  const int boff = (b_n >> 4) * 1024 + b_kq * 256 + (b_n & 15) * 16;
  const float* w2c = w2 + (size_t)e * ID * HD + (size_t)(8 * b_kq) * HD + n0 + b_n;

  const unsigned short* pA0;
  const unsigned short* pA1;
  const unsigned short* pA2;
  const unsigned short* pA3;
  {
    const unsigned short* ub = (const unsigned short*)up;
    int r0 = mstart + wr * 64 + r16;
    int rowA[4];
#pragma unroll
    for (int i = 0; i < 4; ++i) {
      int r = r0 + i * 16;
      rowA[i] = r < TT ? r : TT - 1;
    }
    pA0 = ub + (size_t)rowA[0] * ID + q * 8;
    pA1 = ub + (size_t)rowA[1] * ID + q * 8;
    pA2 = ub + (size_t)rowA[2] * ID + q * 8;
    pA3 = ub + (size_t)rowA[3] * ID + q * 8;
  }

  f32x4 acc[4][2];
#pragma unroll
  for (int i = 0; i < 4; ++i)
#pragma unroll
    for (int j = 0; j < 2; ++j) acc[i][j] = (f32x4)0.f;

  s16x8 Aa[4], Ab[4];
  float Wa[8], Wb[8];

  auto loadA = [&](s16x8* A, int k) {
    A[0] = *(const s16x8*)(pA0 + k * BK);
    A[1] = *(const s16x8*)(pA1 + k * BK);
    A[2] = *(const s16x8*)(pA2 + k * BK);
    A[3] = *(const s16x8*)(pA3 + k * BK);
  };
  auto loadB = [&](float* W_) {
#pragma unroll
    for (int i = 0; i < 8; ++i) W_[i] = w2c[(size_t)i * HD];
    w2c += (size_t)BK * HD;
  };
  auto storeB = [&](int buf, const float* W_) {
    i32x4 p;
    p[0] = (int)f2bfpk(W_[0], W_[1]); p[1] = (int)f2bfpk(W_[2], W_[3]);
    p[2] = (int)f2bfpk(W_[4], W_[5]); p[3] = (int)f2bfpk(W_[6], W_[7]);
    *(i32x4*)(Bs[buf] + boff) = p;
  };
  auto compute = [&](const s16x8* A, int bb) {
    s16x8 b[2];
#pragma unroll
    for (int j = 0; j < 2; ++j)
      b[j] = *(const s16x8*)(Bs[bb] + (wc * 2 + j) * 1024 + lane * 16);
#pragma unroll
    for (int i = 0; i < 4; ++i)
#pragma unroll
      for (int j = 0; j < 2; ++j)
        acc[i][j] = __builtin_amdgcn_mfma_f32_16x16x32_bf16(A[i], b[j], acc[i][j], 0, 0, 0);
  };

  loadA(Aa, 0); loadA(Ab, 1);
  loadB(Wa);   // B(0)
  loadB(Wb);   // B(1)
  storeB(0, Wa);
  lds_barrier();
  for (int kt = 0; kt < NKS2; kt += 2) {
    if (kt + 2 < NKS2) loadB(Wa);
    compute(Aa, 0);
    if (kt + 2 < NKS2) loadA(Aa, kt + 2);
    if (kt + 1 < NKS2) { storeB(1, Wb); lds_barrier(); }
    if (kt + 3 < NKS2) loadB(Wb);
    compute(Ab, 1);
    if (kt + 3 < NKS2) loadA(Ab, kt + 3);
    if (kt + 2 < NKS2) { storeB(0, Wa); lds_barrier(); }
  }

#pragma unroll
  for (int i = 0; i < 4; ++i)
#pragma unroll
    for (int r = 0; r < 4; ++r) {
      int gm = mstart + wr * 64 + i * 16 + q * 4 + r;
      if (gm < rowend) {
#pragma unroll
        for (int j = 0; j < 2; ++j)
          out[(size_t)gm * HD + n0 + wc * 32 + j * 16 + r16] = acc[i][j][r];
      }
    }
}

extern "C" void kernel_launch(void* const* d_in, const int* in_sizes, int n_in,
                              void* d_out, int out_size, void* d_ws, size_t ws_size,
                              hipStream_t stream) {
  const float* x = (const float*)d_in[0];
  const float* w1 = (const float*)d_in[1];
  const float* w2 = (const float*)d_in[2];
  const float* w3 = (const float*)d_in[3];
  const void* bs = d_in[4];
  float* out = (float*)d_out;
  // ws layout: xbf [TT*HD bf16 = 8.39 MB] | up [TT*ID bf16 = 23.07 MB]
  __hip_bfloat16* xbf = (__hip_bfloat16*)d_ws;
  __hip_bfloat16* up = (__hip_bfloat16*)((char*)d_ws + (size_t)TT * HD * 2);

  hipMemsetAsync(d_out, 0, (size_t)out_size * sizeof(float), stream);

  cvt_x<<<dim3(TT * HD / (8 * 256)), dim3(256), 0, stream>>>(x, xbf);
  moe_gemm1<<<dim3((ID / BN1) * MAXMT), dim3(256), 0, stream>>>(xbf, w1, w3, bs, up);
  moe_gemm2<<<dim3((HD / BN2) * MAXMT), dim3(256), 0, stream>>>(up, w2, bs, out);
}

// Round 11
// 205.195 us; speedup vs baseline: 1.4136x; 1.4136x over previous
//
#include <hip/hip_runtime.h>
#include <hip/hip_bf16.h>

#define NE 8
#define HD 1024
#define ID 2816
#define TT 4096
#define BM 128
#define BK 32
#define BN1 64
#define BN2 64
#define MAXMT (TT / BM + NE) /* 40 worst-case M-tiles */
#define NKS1 (HD / BK)  /* 32 */
#define NKS2 (ID / BK)  /* 88 */
#define ATILE 8192      /* BM*BK*2B fragment-order A tile */

typedef __attribute__((ext_vector_type(4))) float f32x4;
typedef __attribute__((ext_vector_type(8))) short s16x8;
typedef __attribute__((ext_vector_type(4))) int i32x4;

// fp32x2 -> packed bf16x2 (RNE, v_cvt_pk_bf16_f32)
__device__ __forceinline__ unsigned int f2bfpk(float lo, float hi) {
  float2 t; t.x = lo; t.y = hi;
  union { __hip_bfloat162 h2; unsigned int u; } cv;
  cv.h2 = __float22bfloat162_rn(t);
  return cv.u;
}

// barrier that does NOT drain vmcnt: prefetch loads stay in flight
__device__ __forceinline__ void lds_barrier() {
  asm volatile("s_waitcnt lgkmcnt(0)" ::: "memory");
  __builtin_amdgcn_s_barrier();
}

// async global->LDS, 16B per lane
__device__ __forceinline__ void glds16(const void* g, void* l) {
  __builtin_amdgcn_global_load_lds(
      (const __attribute__((address_space(1))) void*)g,
      (__attribute__((address_space(3))) void*)l, 16, 0, 0);
}

__device__ __forceinline__ bool map_tile(const void* bsp, int mt, int& e,
                                         int& mstart, int& rowend) {
  const int* w = (const int*)bsp;
  bool is64 = (w[1] == 0) && (w[3] == 0) && (w[5] == 0) && (w[7] == 0) &&
              ((w[0] | w[2] | w[4] | w[6]) != 0);
  long long start = 0;
  int rem = mt;
  for (int i = 0; i < NE; ++i) {
    long long b = is64 ? ((const long long*)bsp)[i] : (long long)w[i];
    if (b < 0) b = 0;
    int tiles = (int)((b + BM - 1) / BM);
    if (rem < tiles) {
      long long m0 = start + (long long)rem * BM;
      long long me = start + b;
      if (m0 >= TT) return false;
      if (me > TT) me = TT;
      e = i; mstart = (int)m0; rowend = (int)me;
      return true;
    }
    rem -= tiles;
    start += b;
  }
  return false;
}

// ---- Kernel 0: x fp32 -> bf16, pre-tiled in MFMA fragment order ----
// [mt][ks][group f=0..7][lane][8 bf16]; group f = rows mstart+f*16+(lane&15),
// cols ks*32+(lane>>4)*8..+7. Rows >= rowend zeroed.
__global__ __launch_bounds__(256) void cvt_xt(const float* __restrict__ x,
                                              const void* __restrict__ bsp,
                                              unsigned short* __restrict__ xt) {
  int mt = blockIdx.x >> 5;
  int ks = blockIdx.x & 31;
  int e, mstart, rowend;
  if (!map_tile(bsp, mt, e, mstart, rowend)) return;
  int t = threadIdx.x;
  int lane = t & 63;
  int r = lane & 15, q = lane >> 4;
  unsigned short* ob = xt + ((size_t)mt * NKS1 + ks) * (ATILE / 2);
#pragma unroll
  for (int h = 0; h < 2; ++h) {
    int f = h * 4 + (t >> 6);
    int row = mstart + f * 16 + r;
    s16x8 o = (s16x8)0;
    if (row < rowend) {
      const float* src = x + (size_t)row * HD + ks * 32 + q * 8;
      f32x4 v0 = *(const f32x4*)src;
      f32x4 v1 = *(const f32x4*)(src + 4);
      unsigned int d0 = f2bfpk(v0[0], v0[1]), d1 = f2bfpk(v0[2], v0[3]);
      unsigned int d2 = f2bfpk(v1[0], v1[1]), d3 = f2bfpk(v1[2], v1[3]);
      o[0] = (short)d0; o[1] = (short)(d0 >> 16);
      o[2] = (short)d1; o[3] = (short)(d1 >> 16);
      o[4] = (short)d2; o[5] = (short)(d2 >> 16);
      o[6] = (short)d3; o[7] = (short)(d3 >> 16);
    }
    *(s16x8*)(ob + h * 2048 + t * 8) = o;
  }
}

// ---------------- Kernel 1: up = silu(x@w1[e]) * (x@w3[e]) ----------------
// 256 thr, 4 waves (2m x 2n). As[2] glds 1-ahead (glds(p+1) issued BEFORE
// loadB(p+1); storeB(p+1)'s vmcnt wait for the newer W loads drains the
// older glds by FIFO). Frag-order B LDS, zero conflicts. One W reg buffer.
// 32KB LDS -> ~5 blk/CU (was 49KB/3blk in the As[4] version).
__global__ __launch_bounds__(256, 4) void moe_gemm1(
    const unsigned short* __restrict__ xt, const float* __restrict__ w1,
    const float* __restrict__ w3, const void* __restrict__ bsp,
    __hip_bfloat16* __restrict__ up) {
  __shared__ __align__(16) char As[2][ATILE];   // 16384
  __shared__ __align__(16) char B1s[2][4096];   // 8192
  __shared__ __align__(16) char B3s[2][4096];   // 8192  -> 32KB

  const int NWG = (ID / BN1) * MAXMT;  // 1760, %8==0
  int bid = blockIdx.x;
  int logical = (bid & 7) * (NWG >> 3) + (bid >> 3);
  int mt = logical % MAXMT;
  int nt = logical / MAXMT;
  int e, mstart, rowend;
  if (!map_tile(bsp, mt, e, mstart, rowend)) return;
  const int n0 = nt * BN1;
  const int tid = threadIdx.x;
  const int lane = tid & 63;
  const int wv = tid >> 6;
  const int wr = wv >> 1, wc = wv & 1;
  const int q = lane >> 4, r16 = lane & 15;

  // B staging: thread (b_n, b_kq) owns col n0+b_n, k = 8*b_kq .. +7
  const int b_n = tid & 63, b_kq = tid >> 6;
  const int boff = (b_n >> 4) * 1024 + b_kq * 256 + (b_n & 15) * 16;
  const char* agp = (const char*)xt + (size_t)mt * NKS1 * ATILE + tid * 16;
  const float* w1c = w1 + (size_t)e * HD * ID + (size_t)(8 * b_kq) * ID + n0 + b_n;
  const float* w3c = w3 + (size_t)e * HD * ID + (size_t)(8 * b_kq) * ID + n0 + b_n;

  f32x4 acc1[4][2], acc3[4][2];
#pragma unroll
  for (int i = 0; i < 4; ++i)
#pragma unroll
    for (int j = 0; j < 2; ++j) { acc1[i][j] = (f32x4)0.f; acc3[i][j] = (f32x4)0.f; }

  float Wc1[8], Wc3[8];  // single W buffer: load at phase start, store at end

  auto gldsA = [&](int k, int buf) {
    const char* s = agp + (size_t)k * ATILE;
    char* d = &As[buf][0] + tid * 16;
    glds16(s, d);
    glds16(s + 4096, d + 4096);
  };
  auto loadB = [&]() {
#pragma unroll
    for (int i = 0; i < 8; ++i) {
      Wc1[i] = w1c[(size_t)i * ID];
      Wc3[i] = w3c[(size_t)i * ID];
    }
    w1c += (size_t)BK * ID; w3c += (size_t)BK * ID;
  };
  auto storeB = [&](int buf) {
    i32x4 p1, p3;
    p1[0] = (int)f2bfpk(Wc1[0], Wc1[1]); p1[1] = (int)f2bfpk(Wc1[2], Wc1[3]);
    p1[2] = (int)f2bfpk(Wc1[4], Wc1[5]); p1[3] = (int)f2bfpk(Wc1[6], Wc1[7]);
    *(i32x4*)(B1s[buf] + boff) = p1;
    p3[0] = (int)f2bfpk(Wc3[0], Wc3[1]); p3[1] = (int)f2bfpk(Wc3[2], Wc3[3]);
    p3[2] = (int)f2bfpk(Wc3[4], Wc3[5]); p3[3] = (int)f2bfpk(Wc3[6], Wc3[7]);
    *(i32x4*)(B3s[buf] + boff) = p3;
  };
  auto compute = [&](int ab, int bb) {
    s16x8 a[4], b1[2], b3[2];
#pragma unroll
    for (int i = 0; i < 4; ++i)
      a[i] = *(const s16x8*)(As[ab] + (wr * 4 + i) * 1024 + lane * 16);
#pragma unroll
    for (int j = 0; j < 2; ++j) {
      b1[j] = *(const s16x8*)(B1s[bb] + (wc * 2 + j) * 1024 + lane * 16);
      b3[j] = *(const s16x8*)(B3s[bb] + (wc * 2 + j) * 1024 + lane * 16);
    }
#pragma unroll
    for (int i = 0; i < 4; ++i)
#pragma unroll
      for (int j = 0; j < 2; ++j) {
        acc1[i][j] = __builtin_amdgcn_mfma_f32_16x16x32_bf16(a[i], b1[j], acc1[i][j], 0, 0, 0);
        acc3[i][j] = __builtin_amdgcn_mfma_f32_16x16x32_bf16(a[i], b3[j], acc3[i][j], 0, 0, 0);
      }
  };

  // prologue: tile 0 staged (storeB's vmcnt wait drains glds(0))
  gldsA(0, 0);
  __builtin_amdgcn_sched_barrier(0);
  loadB();
  storeB(0);
  lds_barrier();
  for (int kt = 0; kt < NKS1; kt += 2) {
    // phase 0: stage kt+1, compute kt (As0/B0)
    if (kt + 1 < NKS1) {
      gldsA(kt + 1, 1);
      __builtin_amdgcn_sched_barrier(0);
      loadB();
      __builtin_amdgcn_sched_barrier(0);
    }
    compute(0, 0);
    if (kt + 1 < NKS1) { storeB(1); lds_barrier(); }
    // phase 1: stage kt+2, compute kt+1 (As1/B1)
    if (kt + 2 < NKS1) {
      gldsA(kt + 2, 0);
      __builtin_amdgcn_sched_barrier(0);
      loadB();
      __builtin_amdgcn_sched_barrier(0);
    }
    compute(1, 1);
    if (kt + 2 < NKS1) { storeB(0); lds_barrier(); }
  }

  // epilogue: silu(acc1)*acc3 -> bf16
#pragma unroll
  for (int i = 0; i < 4; ++i)
#pragma unroll
    for (int r = 0; r < 4; ++r) {
      int gm = mstart + wr * 64 + i * 16 + q * 4 + r;
      if (gm < rowend) {
#pragma unroll
        for (int j = 0; j < 2; ++j) {
          float v1 = acc1[i][j][r], v3 = acc3[i][j][r];
          float s = v1 / (1.f + __expf(-v1));
          up[(size_t)gm * ID + n0 + wc * 32 + j * 16 + r16] = __float2bfloat16(s * v3);
        }
      }
    }
}

// ---------------- Kernel 2: out = up @ w2[e] ----------------
// Same schedule. A glds'd directly from row-major `up` with per-lane
// frag-order source addresses (linear LDS dest). 24KB LDS.
__global__ __launch_bounds__(256, 4) void moe_gemm2(
    const __hip_bfloat16* __restrict__ up, const float* __restrict__ w2,
    const void* __restrict__ bsp, float* __restrict__ out) {
  __shared__ __align__(16) char As[2][ATILE];  // 16384
  __shared__ __align__(16) char Bs[2][4096];   // 8192 -> 24KB

  const int NWG = (HD / BN2) * MAXMT;  // 640, %8==0
  int bid = blockIdx.x;
  int logical = (bid & 7) * (NWG >> 3) + (bid >> 3);
  int mt = logical % MAXMT;
  int nt = logical / MAXMT;
  int e, mstart, rowend;
  if (!map_tile(bsp, mt, e, mstart, rowend)) return;
  const int n0 = nt * BN2;
  const int tid = threadIdx.x;
  const int lane = tid & 63;
  const int wv = tid >> 6;
  const int wr = wv >> 1, wc = wv & 1;
  const int q = lane >> 4, r16 = lane & 15;

  const int b_n = tid & 63, b_kq = tid >> 6;
  const int boff = (b_n >> 4) * 1024 + b_kq * 256 + (b_n & 15) * 16;
  const float* w2c = w2 + (size_t)e * ID * HD + (size_t)(8 * b_kq) * HD + n0 + b_n;

  // glds A sources: thread (g=tid>>6, r=tid&15, q) -> rows g*16+r and +64,
  // 16B of 8 consecutive k. Rows clamped (garbage lands only in output rows
  // >= rowend, which the guarded epilogue discards).
  int row0 = mstart + (tid >> 6) * 16 + (tid & 15);
  int row1 = row0 + 64;
  row0 = row0 < TT ? row0 : TT - 1;
  row1 = row1 < TT ? row1 : TT - 1;
  const char* uc0 = (const char*)up + ((size_t)row0 * ID + q * 8) * 2;
  const char* uc1 = (const char*)up + ((size_t)row1 * ID + q * 8) * 2;

  f32x4 acc[4][2];
#pragma unroll
  for (int i = 0; i < 4; ++i)
#pragma unroll
    for (int j = 0; j < 2; ++j) acc[i][j] = (f32x4)0.f;

  float Wc[8];

  auto gldsA = [&](int buf) {  // sequential k; cursors advance 64B/call
    char* d = &As[buf][0] + tid * 16;
    glds16(uc0, d);
    glds16(uc1, d + 4096);
    uc0 += BK * 2; uc1 += BK * 2;
  };
  auto loadB = [&]() {
#pragma unroll
    for (int i = 0; i < 8; ++i) Wc[i] = w2c[(size_t)i * HD];
    w2c += (size_t)BK * HD;
  };
  auto storeB = [&](int buf) {
    i32x4 p;
    p[0] = (int)f2bfpk(Wc[0], Wc[1]); p[1] = (int)f2bfpk(Wc[2], Wc[3]);
    p[2] = (int)f2bfpk(Wc[4], Wc[5]); p[3] = (int)f2bfpk(Wc[6], Wc[7]);
    *(i32x4*)(Bs[buf] + boff) = p;
  };
  auto compute = [&](int ab, int bb) {
    s16x8 a[4], b[2];
#pragma unroll
    for (int i = 0; i < 4; ++i)
      a[i] = *(const s16x8*)(As[ab] + (wr * 4 + i) * 1024 + lane * 16);
#pragma unroll
    for (int j = 0; j < 2; ++j)
      b[j] = *(const s16x8*)(Bs[bb] + (wc * 2 + j) * 1024 + lane * 16);
#pragma unroll
    for (int i = 0; i < 4; ++i)
#pragma unroll
      for (int j = 0; j < 2; ++j)
        acc[i][j] = __builtin_amdgcn_mfma_f32_16x16x32_bf16(a[i], b[j], acc[i][j], 0, 0, 0);
  };

  gldsA(0);
  __builtin_amdgcn_sched_barrier(0);
  loadB();
  storeB(0);
  lds_barrier();
  for (int kt = 0; kt < NKS2; kt += 2) {
    if (kt + 1 < NKS2) {
      gldsA(1);
      __builtin_amdgcn_sched_barrier(0);
      loadB();
      __builtin_amdgcn_sched_barrier(0);
    }
    compute(0, 0);
    if (kt + 1 < NKS2) { storeB(1); lds_barrier(); }
    if (kt + 2 < NKS2) {
      gldsA(0);
      __builtin_amdgcn_sched_barrier(0);
      loadB();
      __builtin_amdgcn_sched_barrier(0);
    }
    compute(1, 1);
    if (kt + 2 < NKS2) { storeB(0); lds_barrier(); }
  }

#pragma unroll
  for (int i = 0; i < 4; ++i)
#pragma unroll
    for (int r = 0; r < 4; ++r) {
      int gm = mstart + wr * 64 + i * 16 + q * 4 + r;
      if (gm < rowend) {
#pragma unroll
        for (int j = 0; j < 2; ++j)
          out[(size_t)gm * HD + n0 + wc * 32 + j * 16 + r16] = acc[i][j][r];
      }
    }
}

extern "C" void kernel_launch(void* const* d_in, const int* in_sizes, int n_in,
                              void* d_out, int out_size, void* d_ws, size_t ws_size,
                              hipStream_t stream) {
  const float* x = (const float*)d_in[0];
  const float* w1 = (const float*)d_in[1];
  const float* w2 = (const float*)d_in[2];
  const float* w3 = (const float*)d_in[3];
  const void* bs = d_in[4];
  float* out = (float*)d_out;
  // ws: xt tiled [10.49 MB] | up [23.07 MB]
  unsigned short* xt = (unsigned short*)d_ws;
  __hip_bfloat16* up =
      (__hip_bfloat16*)((char*)d_ws + (size_t)MAXMT * NKS1 * ATILE);

  hipMemsetAsync(d_out, 0, (size_t)out_size * sizeof(float), stream);

  cvt_xt<<<dim3(MAXMT * NKS1), dim3(256), 0, stream>>>(x, bs, xt);
  moe_gemm1<<<dim3((ID / BN1) * MAXMT), dim3(256), 0, stream>>>(xt, w1, w3, bs, up);
  moe_gemm2<<<dim3((HD / BN2) * MAXMT), dim3(256), 0, stream>>>(up, w2, bs, out);
}